// Round 9
// baseline (1837.112 us; speedup 1.0000x reference)
//
#include <hip/hip_runtime.h>

typedef long long ll;
typedef __attribute__((ext_vector_type(8))) short short8;
typedef __attribute__((ext_vector_type(4))) float f32x4;
constexpr int HID = 256;
constexpr int LDSS = 264;   // LDS row stride in shorts: 528B, 16B-aligned, ~2-way banks (free)

__device__ inline ushort f2bf(float f){
  uint u = __float_as_uint(f);
  u += 0x7FFFu + ((u >> 16) & 1u);
  return (ushort)(u >> 16);
}

// ---------------- diagnostics ----------------
__global__ void k_diag(float* out, int n, float val){
  int i = blockIdx.x*256 + threadIdx.x;
  if (i < n) out[i] = val;
}

// flag=1 if edge_index is int64 (all high words of first 2048 entries zero)
__global__ void k_detect(const int* ei, int* flag){
  __shared__ int bad;
  if (threadIdx.x == 0) bad = 0;
  __syncthreads();
  for (int i = threadIdx.x; i < 2048; i += 256)
    if (ei[2*i+1] != 0) bad = 1;
  __syncthreads();
  if (threadIdx.x == 0) *flag = bad ? 0 : 1;
}

// ---------------- graph preprocessing ----------------
__global__ void k_count(const int* ei, ll E, const int* flag, int* cnt){
  ll i = (ll)blockIdx.x*256 + threadIdx.x;
  if (i >= E) return;
  int f = *flag;
  int d = f ? (int)((const ll*)ei)[E + i] : ei[E + i];
  atomicAdd(&cnt[d], 1);
}

__global__ void k_dinv(const int* cnt, const float* x, float* dinv, float* xd, int n){
  int i = blockIdx.x*256 + threadIdx.x;
  if (i > n) return;
  if (i == n){ xd[n] = 0.f; return; }          // dummy zero entry for padded gathers
  float dv = 1.0f / sqrtf((float)(cnt[i] + 1));
  dinv[i] = dv;
  xd[i] = x[i] * dv;
}

// iteration count per node: it = ceil((cnt+1)/8); histogram over bucket min(it,255)
__global__ void k_hist(const int* __restrict__ cnt, int* __restrict__ hist, int n){
  int i = blockIdx.x*256 + threadIdx.x;
  if (i >= n) return;
  int it = (cnt[i] + 8) >> 3;
  atomicAdd(&hist[min(it, 255)], 1);
}

// exclusive scans of bucket counts (positions) and count*it (slot base, /8)
__global__ void k_hscan(const int* __restrict__ hist, int* __restrict__ posStart,
                        int* __restrict__ itBase, int* __restrict__ itFill){
  __shared__ int sc[256], sw[256];
  int t = threadIdx.x;
  int c = hist[t];
  int w = (t < 255) ? c*t : 0;
  sc[t] = c; sw[t] = w; __syncthreads();
  for (int off = 1; off < 256; off <<= 1){
    int ac = (t >= off) ? sc[t-off] : 0;
    int aw = (t >= off) ? sw[t-off] : 0;
    __syncthreads();
    sc[t] += ac; sw[t] += aw;
    __syncthreads();
  }
  posStart[t] = sc[t] - c;
  itBase[t]  = sw[t] - w;
  if (t == 255) itFill[0] = sw[255];   // heterogeneous bucket allocates from here
}

// place node into sorted order; init padded slots (self-loop at slot 0, zero-row padding)
__global__ void k_placeN(const int* __restrict__ cnt, const int* __restrict__ posStart,
                         const int* __restrict__ itBase, int* posFill, int* itFill,
                         int* __restrict__ ord, int* __restrict__ pstart, int* __restrict__ pit,
                         int* __restrict__ pbase, int* __restrict__ pfill,
                         uint* __restrict__ colb, int n){
  int i = blockIdx.x*256 + threadIdx.x;
  if (i >= n) return;
  int deg = cnt[i] + 1;                 // in-edges + self
  int it  = (deg + 7) >> 3;
  int b   = min(it, 255);
  int r   = atomicAdd(&posFill[b], 1);
  int pos = posStart[b] + r;
  int ps  = (b < 255) ? (itBase[b] + r*b) : atomicAdd(itFill, it);
  int base = ps * 8;
  ord[pos]    = i;
  pstart[pos] = base;
  pit[pos]    = it;
  pbase[i]    = base;
  colb[base]  = (uint)i * 64u;          // self-loop
  pfill[i]    = base + 1;
  int tot = it * 8;
  for (int k = deg; k < tot; ++k) colb[base + k] = (uint)n * 64u;  // zero-row pads
}

__global__ void k_placeE(const int* ei, ll E, const int* flag, int* pfill, uint* colb){
  ll i = (ll)blockIdx.x*256 + threadIdx.x;
  if (i >= E) return;
  int f = *flag;
  int s, d;
  if (f){ const ll* e64 = (const ll*)ei; s = (int)e64[i]; d = (int)e64[E + i]; }
  else  { s = ei[i]; d = ei[E + i]; }
  int p = atomicAdd(&pfill[d], 1);
  colb[p] = (uint)s * 64u;
}

// layer 1 is rank-1: g[d] = sum over padded slots of xd[col]  (self included, pads read xd[n]=0)
__global__ void k_layer1p(const float* __restrict__ xd, const int* __restrict__ cnt,
                          const int* __restrict__ pbase, const uint* __restrict__ colb,
                          float* __restrict__ g, int n){
  int i = blockIdx.x*256 + threadIdx.x;
  if (i >= n) return;
  int base = pbase[i];
  int tot = ((cnt[i] + 8) >> 3) * 8;
  float s = 0.f;
  for (int k = 0; k < tot; ++k) s += xd[colb[base + k] >> 6];
  g[i] = s;
}

// ---------------- W split: fp32 -> (hi,lo) bf16, MFMA-fragment-major ----------------
__global__ void k_splitW(const float* __restrict__ W, short* __restrict__ Bt){
  int idx = blockIdx.x*256 + threadIdx.x;
  if (idx >= 16*8*64) return;
  int nb = idx >> 9, kc = (idx >> 6) & 7, l = idx & 63;
  short8 hi, lo;
  #pragma unroll
  for (int j = 0; j < 8; ++j){
    int k = kc*32 + ((l >> 4) * 8) + j;
    int c = nb*16 + (l & 15);
    float wv = W[k*HID + c];
    ushort h = f2bf(wv);
    float hf = __uint_as_float((uint)h << 16);
    hi[j] = (short)h;
    lo[j] = (short)f2bf(wv - hf);
  }
  ((short8*)Bt)[idx] = hi;
  ((short8*)Bt)[8192 + idx] = lo;
}

// ---------------- MFMA GEMM: ts_bf = bf16( (A @ W) * dinv_row ), SLICE-MAJOR output ----------
// ts_bf layout: [8 slices][N+1 rows][32 feats] bf16 (row N = zeros, never written).
// Abf layout:   [8 slices][N rows][32 feats] bf16.
template<int MODE>
__global__ __launch_bounds__(256, 4) void k_gemm_mfma(
  const void* __restrict__ Ain, const short* __restrict__ Bt,
  const float* __restrict__ bias, const float* __restrict__ W1,
  const float* __restrict__ dinv, ushort* __restrict__ ts_bf, int n)
{
  __shared__ short Ah[64*LDSS];   // 33.8 KB
  int t = threadIdx.x;
  int r0 = blockIdx.x * 64;

  #pragma unroll
  for (int i = 0; i < 8; ++i){
    if (MODE == 0){
      int id  = i*256 + t;
      int row = id >> 5;
      int c16 = id & 31;
      int v   = r0 + row;
      short8 hi8 = {0,0,0,0,0,0,0,0};
      if (v < n){
        float gv = dinv[v] * ((const float*)Ain)[v];
        const float4* wp = (const float4*)(W1 + c16*8);
        const float4* bp = (const float4*)(bias + c16*8);
        float4 w0 = wp[0], w1 = wp[1], b0 = bp[0], b1 = bp[1];
        hi8[0] = (short)f2bf(fmaxf(fmaf(gv,w0.x,b0.x), 0.f));
        hi8[1] = (short)f2bf(fmaxf(fmaf(gv,w0.y,b0.y), 0.f));
        hi8[2] = (short)f2bf(fmaxf(fmaf(gv,w0.z,b0.z), 0.f));
        hi8[3] = (short)f2bf(fmaxf(fmaf(gv,w0.w,b0.w), 0.f));
        hi8[4] = (short)f2bf(fmaxf(fmaf(gv,w1.x,b1.x), 0.f));
        hi8[5] = (short)f2bf(fmaxf(fmaf(gv,w1.y,b1.y), 0.f));
        hi8[6] = (short)f2bf(fmaxf(fmaf(gv,w1.z,b1.z), 0.f));
        hi8[7] = (short)f2bf(fmaxf(fmaf(gv,w1.w,b1.w), 0.f));
      }
      *(short8*)&Ah[row*LDSS + c16*8] = hi8;
    } else {
      int row = t >> 2, off = t & 3;
      int v = r0 + row;
      short8 hi8 = {0,0,0,0,0,0,0,0};
      if (v < n)
        hi8 = ((const short8*)Ain)[(size_t)i*n*4 + (size_t)v*4 + off];
      *(short8*)&Ah[row*LDSS + (i*4 + off)*8] = hi8;
    }
  }
  __syncthreads();

  int l = t & 63, w = t >> 6;
  const short8* Btv = (const short8*)Bt;
  f32x4 acc[4][4];
  #pragma unroll
  for (int m = 0; m < 4; ++m)
    #pragma unroll
    for (int nf = 0; nf < 4; ++nf)
      acc[m][nf] = (f32x4){0.f,0.f,0.f,0.f};

  for (int kc = 0; kc < 8; ++kc){
    short8 ah[4];
    #pragma unroll
    for (int m = 0; m < 4; ++m){
      int row = m*16 + (l & 15);
      ah[m] = *(const short8*)&Ah[row*LDSS + (kc*4 + (l >> 4))*8];
    }
    #pragma unroll
    for (int nf = 0; nf < 4; ++nf){
      int nb = w*4 + nf;
      short8 bh = Btv[(size_t)(nb*8 + kc)*64 + l];
      short8 bl = Btv[(size_t)8192 + (nb*8 + kc)*64 + l];
      #pragma unroll
      for (int m = 0; m < 4; ++m){
        acc[m][nf] = __builtin_amdgcn_mfma_f32_16x16x32_bf16(ah[m], bh, acc[m][nf], 0,0,0);
        acc[m][nf] = __builtin_amdgcn_mfma_f32_16x16x32_bf16(ah[m], bl, acc[m][nf], 0,0,0);
      }
    }
  }

  #pragma unroll
  for (int m = 0; m < 4; ++m){
    int rowb = r0 + m*16 + ((l >> 4)*4);
    #pragma unroll
    for (int r = 0; r < 4; ++r){
      int v = rowb + r;
      if (v < n){
        float dv = dinv[v];
        #pragma unroll
        for (int nf = 0; nf < 4; ++nf){
          int colb = w*64 + nf*16 + (l & 15);
          int slice = colb >> 5, within = colb & 31;
          ts_bf[(size_t)slice*(n+1)*32 + (size_t)v*32 + within] = f2bf(dv * acc[m][nf][r]);
        }
      }
    }
  }
}

// ---------------- propagate + fused transform: sorted, padded, divergence-free ----------------
// Block b: slice = b&7 (slice stays on one XCD's L2), sorted-node group = b>>3 (32 nodes/block).
// Wave = 8 groups x 8 feat-lanes; group g owns ONE node; lane f owns feat-chunk f (8B).
// Padded CSR: inner loop has NO predication; degree-sorted order: no group divergence.
// No cross-lane fold: all 8 slots accumulate in the same lanes.
__device__ inline void bfacc(uint2 u, float4& a){
  a.x += __uint_as_float(u.x << 16);
  a.y += __uint_as_float(u.x & 0xFFFF0000u);
  a.z += __uint_as_float(u.y << 16);
  a.w += __uint_as_float(u.y & 0xFFFF0000u);
}

__global__ __launch_bounds__(256, 4) void k_scatter_ps(
  const ushort* __restrict__ ts_bf, const int* __restrict__ ord,
  const int* __restrict__ pstart, const int* __restrict__ pit,
  const uint* __restrict__ colb, const float* __restrict__ bias,
  const float* __restrict__ dinv, ushort* __restrict__ Abf, int n)
{
  int b = blockIdx.x;
  int s = b & 7;
  int t = threadIdx.x;
  int g = (t >> 3) & 7;
  int w = t >> 6;
  int f = t & 7;
  int sp = (b >> 3)*32 + w*8 + g;
  bool valid = sp < n;
  int it = valid ? pit[sp] : 0;
  int e  = valid ? pstart[sp] : 0;
  const char* base = (const char*)ts_bf + (size_t)s*(n+1)*64 + (size_t)f*8;

  float4 a0 = make_float4(0.f,0.f,0.f,0.f);
  float4 a1 = make_float4(0.f,0.f,0.f,0.f);
  float4 a2 = make_float4(0.f,0.f,0.f,0.f);
  float4 a3 = make_float4(0.f,0.f,0.f,0.f);

  for (int i = 0; i < it; ++i){
    uint c0 = __builtin_nontemporal_load(colb + e + 0);
    uint c1 = __builtin_nontemporal_load(colb + e + 1);
    uint c2 = __builtin_nontemporal_load(colb + e + 2);
    uint c3 = __builtin_nontemporal_load(colb + e + 3);
    uint c4 = __builtin_nontemporal_load(colb + e + 4);
    uint c5 = __builtin_nontemporal_load(colb + e + 5);
    uint c6 = __builtin_nontemporal_load(colb + e + 6);
    uint c7 = __builtin_nontemporal_load(colb + e + 7);
    uint2 v0 = *(const uint2*)(base + c0);
    uint2 v1 = *(const uint2*)(base + c1);
    uint2 v2 = *(const uint2*)(base + c2);
    uint2 v3 = *(const uint2*)(base + c3);
    uint2 v4 = *(const uint2*)(base + c4);
    uint2 v5 = *(const uint2*)(base + c5);
    uint2 v6 = *(const uint2*)(base + c6);
    uint2 v7 = *(const uint2*)(base + c7);
    bfacc(v0, a0); bfacc(v1, a1); bfacc(v2, a2); bfacc(v3, a3);
    bfacc(v4, a0); bfacc(v5, a1); bfacc(v6, a2); bfacc(v7, a3);
    e += 8;
  }

  a0.x += a1.x + a2.x + a3.x;
  a0.y += a1.y + a2.y + a3.y;
  a0.z += a1.z + a2.z + a3.z;
  a0.w += a1.w + a2.w + a3.w;

  if (valid){
    int node = ord[sp];
    float dv = dinv[node];
    float4 bb = *(const float4*)(bias + s*32 + f*4);
    uint2 o;
    o.x = (uint)f2bf(fmaxf(fmaf(dv, a0.x, bb.x), 0.f))
        | ((uint)f2bf(fmaxf(fmaf(dv, a0.y, bb.y), 0.f)) << 16);
    o.y = (uint)f2bf(fmaxf(fmaf(dv, a0.z, bb.z), 0.f))
        | ((uint)f2bf(fmaxf(fmaf(dv, a0.w, bb.w), 0.f)) << 16);
    ((uint2*)Abf)[(size_t)s*n*8 + (size_t)node*8 + f] = o;
  }
}

// ---------------- final: out[v] = Abf[v] . Wc + bc  (Abf slice-major) ----------------
__global__ __launch_bounds__(256) void k_out(
  const ushort* __restrict__ Abf, const float* __restrict__ Wc,
  const float* __restrict__ bc, float* __restrict__ out, int n)
{
  int w = (int)((blockIdx.x*256 + threadIdx.x) >> 6);
  int lane = threadIdx.x & 63;
  if (w >= n) return;
  uint2 u = ((const uint2*)Abf)[(size_t)(lane >> 3)*n*8 + (size_t)w*8 + (lane & 7)];
  float4 wc = ((const float4*)Wc)[lane];
  float s = __uint_as_float(u.x << 16)          * wc.x
          + __uint_as_float(u.x & 0xFFFF0000u)  * wc.y
          + __uint_as_float(u.y << 16)          * wc.z
          + __uint_as_float(u.y & 0xFFFF0000u)  * wc.w;
  #pragma unroll
  for (int off = 32; off; off >>= 1) s += __shfl_down(s, off, 64);
  if (lane == 0) out[w] = s + bc[0];
}

// ---------------- launch ----------------
extern "C" void kernel_launch(void* const* d_in, const int* in_sizes, int n_in,
                              void* d_out, int out_size, void* d_ws, size_t ws_size,
                              hipStream_t stream)
{
  const float* x  = (const float*)d_in[0];
  const int*   ei = (const int*)d_in[1];
  const float* W1 = (const float*)d_in[2];
  const float* b1 = (const float*)d_in[3];
  const float* Wm = (const float*)d_in[4];
  const float* bm = (const float*)d_in[5];
  const float* Wc = (const float*)d_in[6];
  const float* bc = (const float*)d_in[7];
  float* out = (float*)d_out;
  const int N = in_sizes[0];
  const ll  E = in_sizes[1] / 2;

  char* ws = (char*)d_ws;
  size_t off = 0;
  auto carve = [&](size_t bytes)->char*{
    char* p = ws + off; off += (bytes + 255) & ~(size_t)255; return p;
  };
  int*   cnt      = (int*)  carve((size_t)N*4);
  float* dinv     = (float*)carve((size_t)N*4);
  float* xd       = (float*)carve((size_t)(N+1)*4);
  float* g        = (float*)carve((size_t)N*4);
  int*   flag     = (int*)  carve(256);
  int*   hist     = (int*)  carve(1024);
  int*   posStart = (int*)  carve(1024);
  int*   itBase   = (int*)  carve(1024);
  int*   posFill  = (int*)  carve(1024);
  int*   itFill   = (int*)  carve(256);
  int*   ord      = (int*)  carve((size_t)N*4);
  int*   pstart   = (int*)  carve((size_t)N*4);
  int*   pit      = (int*)  carve((size_t)N*4);
  int*   pbase    = (int*)  carve((size_t)N*4);
  int*   pfill    = (int*)  carve((size_t)N*4);
  short* Bt       = (short*)carve((size_t)2*8192*8*2);        // 256 KB
  uint*  colb     = (uint*) carve(((size_t)E + 8*(size_t)N + 2048)*4);  // padded CSR (byte offsets)
  ushort* ts_bf   = (ushort*)carve((size_t)8*(N+1)*32*2);     // slice-major, +zero row
  ushort* Abf     = (ushort*)carve((size_t)N*HID*2);          // slice-major
  if (off > ws_size){
    k_diag<<<(out_size+255)/256, 256, 0, stream>>>(out, out_size, (float)(ws_size >> 20));
    return;
  }

  hipMemsetAsync(cnt, 0, (size_t)N*4, stream);
  hipMemsetAsync(hist, 0, 1024, stream);
  hipMemsetAsync(posFill, 0, 1024, stream);
  hipMemsetAsync(ts_bf, 0, (size_t)8*(N+1)*32*2, stream);   // zero rows (row N per slice) stay 0

  k_detect<<<1, 256, 0, stream>>>(ei, flag);
  int eblocks = (int)((E + 255) / 256);
  int nblocks = (N + 255) / 256;
  k_count<<<eblocks, 256, 0, stream>>>(ei, E, flag, cnt);
  k_dinv<<<(N+256)/256, 256, 0, stream>>>(cnt, x, dinv, xd, N);
  k_hist<<<nblocks, 256, 0, stream>>>(cnt, hist, N);
  k_hscan<<<1, 256, 0, stream>>>(hist, posStart, itBase, itFill);
  k_placeN<<<nblocks, 256, 0, stream>>>(cnt, posStart, itBase, posFill, itFill,
                                        ord, pstart, pit, pbase, pfill, colb, N);
  k_placeE<<<eblocks, 256, 0, stream>>>(ei, E, flag, pfill, colb);
  k_splitW<<<32, 256, 0, stream>>>(Wm, Bt);
  k_layer1p<<<nblocks, 256, 0, stream>>>(xd, cnt, pbase, colb, g, N);

  int gblocks = (N + 63) / 64;
  int sblocks = 8 * ((N + 31) / 32);
  int oblocks = (N + 3) / 4;
  k_gemm_mfma<0><<<gblocks, 256, 0, stream>>>(g, Bt, b1, W1, dinv, ts_bf, N);
  k_scatter_ps<<<sblocks, 256, 0, stream>>>(ts_bf, ord, pstart, pit, colb, bm, dinv, Abf, N);
  for (int l = 0; l < 8; ++l){
    k_gemm_mfma<1><<<gblocks, 256, 0, stream>>>(Abf, Bt, bm, nullptr, dinv, ts_bf, N);
    k_scatter_ps<<<sblocks, 256, 0, stream>>>(ts_bf, ord, pstart, pit, colb, bm, dinv, Abf, N);
  }
  k_out<<<oblocks, 256, 0, stream>>>(Abf, Wc, bc, out, N);
}

// Round 10
// 869.139 us; speedup vs baseline: 2.1137x; 2.1137x over previous
//
#include <hip/hip_runtime.h>

typedef long long ll;
typedef __attribute__((ext_vector_type(8))) short short8;
typedef __attribute__((ext_vector_type(4))) float f32x4;
constexpr int HID = 256;
constexpr int LDSS = 264;   // LDS row stride in shorts: 528B, 16B-aligned, ~2-way banks (free)

__device__ inline ushort f2bf(float f){
  uint u = __float_as_uint(f);
  u += 0x7FFFu + ((u >> 16) & 1u);
  return (ushort)(u >> 16);
}

// ---------------- diagnostics ----------------
__global__ void k_diag(float* out, int n, float val){
  int i = blockIdx.x*256 + threadIdx.x;
  if (i < n) out[i] = val;
}

// flag=1 if edge_index is int64 (all high words of first 2048 entries zero)
__global__ void k_detect(const int* ei, int* flag){
  __shared__ int bad;
  if (threadIdx.x == 0) bad = 0;
  __syncthreads();
  for (int i = threadIdx.x; i < 2048; i += 256)
    if (ei[2*i+1] != 0) bad = 1;
  __syncthreads();
  if (threadIdx.x == 0) *flag = bad ? 0 : 1;
}

// ---------------- graph preprocessing ----------------
__global__ void k_count(const int* ei, ll E, const int* flag, int* cnt){
  ll i = (ll)blockIdx.x*256 + threadIdx.x;
  if (i >= E) return;
  int f = *flag;
  int d = f ? (int)((const ll*)ei)[E + i] : ei[E + i];
  atomicAdd(&cnt[d], 1);
}

// ---- multi-block scan ----
__global__ void k_scan_a(const int* __restrict__ cnt, int* __restrict__ bsum, int n){
  __shared__ int s[256];
  int t = threadIdx.x, i = blockIdx.x*256 + t;
  s[t] = (i < n) ? cnt[i] : 0;
  __syncthreads();
  for (int off = 128; off; off >>= 1){
    if (t < off) s[t] += s[t + off];
    __syncthreads();
  }
  if (t == 0) bsum[blockIdx.x] = s[0];
}

__global__ void k_scan_b(const int* __restrict__ bsum, int* __restrict__ boff,
                         int nb, int* __restrict__ row_ptr, int n){
  __shared__ int s[256];
  int t = threadIdx.x;
  int v = (t < nb) ? bsum[t] : 0;
  s[t] = v; __syncthreads();
  for (int off = 1; off < 256; off <<= 1){
    int add = (t >= off) ? s[t - off] : 0;
    __syncthreads();
    s[t] += add;
    __syncthreads();
  }
  if (t < nb) boff[t] = s[t] - v;
  if (t == nb - 1) row_ptr[n] = s[t];
}

__global__ void k_scan_c(const int* __restrict__ cnt, const int* __restrict__ boff,
                         int* __restrict__ row_ptr, int n){
  __shared__ int s[256];
  int t = threadIdx.x, i = blockIdx.x*256 + t;
  int v = (i < n) ? cnt[i] : 0;
  s[t] = v; __syncthreads();
  for (int off = 1; off < 256; off <<= 1){
    int add = (t >= off) ? s[t - off] : 0;
    __syncthreads();
    s[t] += add;
    __syncthreads();
  }
  if (i < n) row_ptr[i] = boff[blockIdx.x] + s[t] - v;
}

__global__ void k_dinv(const int* cnt, const float* x, float* dinv, float* xd, int n){
  int i = blockIdx.x*256 + threadIdx.x;
  if (i >= n) return;
  float dv = 1.0f / sqrtf((float)(cnt[i] + 1));
  dinv[i] = dv;
  xd[i] = x[i] * dv;
}

__global__ void k_place(const int* ei, ll E, const int* flag, int* fill, int* col){
  ll i = (ll)blockIdx.x*256 + threadIdx.x;
  if (i >= E) return;
  int f = *flag;
  int s, d;
  if (f){ const ll* e64 = (const ll*)ei; s = (int)e64[i]; d = (int)e64[E + i]; }
  else  { s = ei[i]; d = ei[E + i]; }
  int p = atomicAdd(&fill[d], 1);
  col[p] = s;
}

// layer 1 is rank-1: g[d] = xd[d] + sum_{s->d} xd[s]
__global__ void k_layer1(const float* __restrict__ xd, const int* __restrict__ row_ptr,
                         const int* __restrict__ col, float* __restrict__ g, int n){
  int i = blockIdx.x*256 + threadIdx.x;
  if (i >= n) return;
  float s = xd[i];
  int e0 = row_ptr[i], e1 = row_ptr[i+1];
  for (int e = e0; e < e1; ++e) s += xd[col[e]];
  g[i] = s;
}

// ---------------- W split: fp32 -> (hi,lo) bf16, MFMA-fragment-major ----------------
__global__ void k_splitW(const float* __restrict__ W, short* __restrict__ Bt){
  int idx = blockIdx.x*256 + threadIdx.x;
  if (idx >= 16*8*64) return;
  int nb = idx >> 9, kc = (idx >> 6) & 7, l = idx & 63;
  short8 hi, lo;
  #pragma unroll
  for (int j = 0; j < 8; ++j){
    int k = kc*32 + ((l >> 4) * 8) + j;
    int c = nb*16 + (l & 15);
    float wv = W[k*HID + c];
    ushort h = f2bf(wv);
    float hf = __uint_as_float((uint)h << 16);
    hi[j] = (short)h;
    lo[j] = (short)f2bf(wv - hf);
  }
  ((short8*)Bt)[idx] = hi;
  ((short8*)Bt)[8192 + idx] = lo;
}

// ---------------- MFMA GEMM: ts_bf = bf16( (A @ W) * dinv_row ) ----------------
// MODE 0: A[v][k] = bf16(relu(dinv[v]*g[v]*W1[k] + b1[k]))   (computed inline from scalar g)
// MODE 1: A = Abf (bf16, node-major, transform already applied by scatter epilogue)
// W = Bh + Bl exact (hi/lo bf16 split): C = Ah*Bh + Ah*Bl, fp32 accumulate.
template<int MODE>
__global__ __launch_bounds__(256, 4) void k_gemm_mfma(
  const void* __restrict__ Ain, const short* __restrict__ Bt,
  const float* __restrict__ bias, const float* __restrict__ W1,
  const float* __restrict__ dinv, ushort* __restrict__ ts_bf, int n)
{
  __shared__ short Ah[64*LDSS];   // 33.8 KB
  int t = threadIdx.x;
  int r0 = blockIdx.x * 64;

  // ---- stage A tile: 64 rows x 256 bf16 ----
  #pragma unroll
  for (int i = 0; i < 8; ++i){
    int id  = i*256 + t;           // 16B-chunk id, 0..2047
    int row = id >> 5;             // 0..63
    int c16 = id & 31;             // 16B chunk (8 feats) within row
    int v   = r0 + row;
    short8 hi8 = {0,0,0,0,0,0,0,0};
    if (v < n){
      if (MODE == 0){
        float gv = dinv[v] * ((const float*)Ain)[v];
        const float4* wp = (const float4*)(W1 + c16*8);
        const float4* bp = (const float4*)(bias + c16*8);
        float4 w0 = wp[0], w1 = wp[1], b0 = bp[0], b1 = bp[1];
        hi8[0] = (short)f2bf(fmaxf(fmaf(gv,w0.x,b0.x), 0.f));
        hi8[1] = (short)f2bf(fmaxf(fmaf(gv,w0.y,b0.y), 0.f));
        hi8[2] = (short)f2bf(fmaxf(fmaf(gv,w0.z,b0.z), 0.f));
        hi8[3] = (short)f2bf(fmaxf(fmaf(gv,w0.w,b0.w), 0.f));
        hi8[4] = (short)f2bf(fmaxf(fmaf(gv,w1.x,b1.x), 0.f));
        hi8[5] = (short)f2bf(fmaxf(fmaf(gv,w1.y,b1.y), 0.f));
        hi8[6] = (short)f2bf(fmaxf(fmaf(gv,w1.z,b1.z), 0.f));
        hi8[7] = (short)f2bf(fmaxf(fmaf(gv,w1.w,b1.w), 0.f));
      } else {
        hi8 = ((const short8*)Ain)[(size_t)v*32 + c16];
      }
    }
    *(short8*)&Ah[row*LDSS + c16*8] = hi8;
  }
  __syncthreads();

  // ---- MFMA: wave w covers cols [w*64, w*64+64) ----
  int l = t & 63, w = t >> 6;
  const short8* Btv = (const short8*)Bt;
  f32x4 acc[4][4];
  #pragma unroll
  for (int m = 0; m < 4; ++m)
    #pragma unroll
    for (int nf = 0; nf < 4; ++nf)
      acc[m][nf] = (f32x4){0.f,0.f,0.f,0.f};

  for (int kc = 0; kc < 8; ++kc){
    short8 ah[4];
    #pragma unroll
    for (int m = 0; m < 4; ++m){
      int row = m*16 + (l & 15);
      ah[m] = *(const short8*)&Ah[row*LDSS + (kc*4 + (l >> 4))*8];
    }
    #pragma unroll
    for (int nf = 0; nf < 4; ++nf){
      int nb = w*4 + nf;
      short8 bh = Btv[(size_t)(nb*8 + kc)*64 + l];
      short8 bl = Btv[(size_t)8192 + (nb*8 + kc)*64 + l];
      #pragma unroll
      for (int m = 0; m < 4; ++m){
        acc[m][nf] = __builtin_amdgcn_mfma_f32_16x16x32_bf16(ah[m], bh, acc[m][nf], 0,0,0);
        acc[m][nf] = __builtin_amdgcn_mfma_f32_16x16x32_bf16(ah[m], bl, acc[m][nf], 0,0,0);
      }
    }
  }

  // ---- store ts_bf, pre-scaled by dinv[src] ----
  #pragma unroll
  for (int m = 0; m < 4; ++m){
    int rowb = r0 + m*16 + ((l >> 4)*4);
    #pragma unroll
    for (int r = 0; r < 4; ++r){
      int v = rowb + r;
      if (v < n){
        float dv = dinv[v];
        #pragma unroll
        for (int nf = 0; nf < 4; ++nf){
          int colb = w*64 + nf*16 + (l & 15);
          ts_bf[(size_t)v*HID + colb] = f2bf(dv * acc[m][nf][r]);
        }
      }
    }
  }
}

// ---------------- propagate + fused transform (node-major, 8-deep MLP) ----------------
// sum = ts[d] + sum_{e} ts[col[e]]  (fp32 accum over bf16 rows)
// LAST=0: Abf[d] = bf16( relu(dinv[d]*sum + b) )  — next layer's A
// LAST=1: out[d] = relu(dinv[d]*sum + b) . Wc + bc  (readout fused; no Abf write)
__device__ inline void bfacc(uint2 u, float4& a){
  a.x += __uint_as_float(u.x << 16);
  a.y += __uint_as_float(u.x & 0xFFFF0000u);
  a.z += __uint_as_float(u.y << 16);
  a.w += __uint_as_float(u.y & 0xFFFF0000u);
}

template<int LAST>
__global__ __launch_bounds__(256, 4) void k_scatter_bf(
  const ushort* __restrict__ ts_bf, const int* __restrict__ row_ptr,
  const int* __restrict__ col, const float* __restrict__ bias,
  const float* __restrict__ dinv, ushort* __restrict__ Abf,
  const float* __restrict__ Wc, const float* __restrict__ bc,
  float* __restrict__ out, int n)
{
  int w = (int)((blockIdx.x*256 + threadIdx.x) >> 6);
  int lane = threadIdx.x & 63;
  if (w >= n) return;
  const uint2* tsp = ((const uint2*)ts_bf) + lane;   // row c at + c*64
  int e0 = row_ptr[w], e1 = row_ptr[w+1];

  float4 a0 = make_float4(0.f,0.f,0.f,0.f);
  float4 a1 = make_float4(0.f,0.f,0.f,0.f);
  float4 a2 = make_float4(0.f,0.f,0.f,0.f);
  float4 a3 = make_float4(0.f,0.f,0.f,0.f);
  bfacc(tsp[(size_t)w*64], a0);                      // self-loop term

  int e = e0;
  for (; e + 8 <= e1; e += 8){                       // 8 loads in flight
    int c[8];
    #pragma unroll
    for (int j = 0; j < 8; ++j) c[j] = __builtin_nontemporal_load(col + e + j);
    uint2 v[8];
    #pragma unroll
    for (int j = 0; j < 8; ++j) v[j] = tsp[(size_t)c[j]*64];
    bfacc(v[0], a0); bfacc(v[1], a1); bfacc(v[2], a2); bfacc(v[3], a3);
    bfacc(v[4], a0); bfacc(v[5], a1); bfacc(v[6], a2); bfacc(v[7], a3);
  }
  for (; e + 2 <= e1; e += 2){
    int c0 = __builtin_nontemporal_load(col + e);
    int c1 = __builtin_nontemporal_load(col + e + 1);
    uint2 v0 = tsp[(size_t)c0*64];
    uint2 v1 = tsp[(size_t)c1*64];
    bfacc(v0, a0); bfacc(v1, a1);
  }
  if (e < e1){
    uint2 v = tsp[(size_t)__builtin_nontemporal_load(col + e)*64];
    bfacc(v, a0);
  }

  a0.x += a1.x + a2.x + a3.x;
  a0.y += a1.y + a2.y + a3.y;
  a0.z += a1.z + a2.z + a3.z;
  a0.w += a1.w + a2.w + a3.w;

  float dv = dinv[w];
  float4 bb = ((const float4*)bias)[lane];
  if (LAST == 0){
    // fused transform: next A = bf16(relu(dinv*sum + b))
    uint2 o;
    o.x = (uint)f2bf(fmaxf(fmaf(dv, a0.x, bb.x), 0.f))
        | ((uint)f2bf(fmaxf(fmaf(dv, a0.y, bb.y), 0.f)) << 16);
    o.y = (uint)f2bf(fmaxf(fmaf(dv, a0.z, bb.z), 0.f))
        | ((uint)f2bf(fmaxf(fmaf(dv, a0.w, bb.w), 0.f)) << 16);
    ((uint2*)Abf)[(size_t)w*64 + lane] = o;
  } else {
    // fused readout: out[w] = relu(dinv*sum + b) . Wc + bc
    float4 wc = ((const float4*)Wc)[lane];
    float s = fmaxf(fmaf(dv, a0.x, bb.x), 0.f)*wc.x
            + fmaxf(fmaf(dv, a0.y, bb.y), 0.f)*wc.y
            + fmaxf(fmaf(dv, a0.z, bb.z), 0.f)*wc.z
            + fmaxf(fmaf(dv, a0.w, bb.w), 0.f)*wc.w;
    #pragma unroll
    for (int off = 32; off; off >>= 1) s += __shfl_down(s, off, 64);
    if (lane == 0) out[w] = s + bc[0];
  }
}

// ---------------- launch ----------------
extern "C" void kernel_launch(void* const* d_in, const int* in_sizes, int n_in,
                              void* d_out, int out_size, void* d_ws, size_t ws_size,
                              hipStream_t stream)
{
  const float* x  = (const float*)d_in[0];
  const int*   ei = (const int*)d_in[1];
  const float* W1 = (const float*)d_in[2];
  const float* b1 = (const float*)d_in[3];
  const float* Wm = (const float*)d_in[4];
  const float* bm = (const float*)d_in[5];
  const float* Wc = (const float*)d_in[6];
  const float* bc = (const float*)d_in[7];
  float* out = (float*)d_out;
  const int N = in_sizes[0];
  const ll  E = in_sizes[1] / 2;

  char* ws = (char*)d_ws;
  size_t off = 0;
  auto carve = [&](size_t bytes)->char*{
    char* p = ws + off; off += (bytes + 255) & ~(size_t)255; return p;
  };
  int*   cnt     = (int*)  carve((size_t)N*4);
  int*   row_ptr = (int*)  carve((size_t)(N+1)*4);
  int*   fill    = (int*)  carve((size_t)N*4);
  float* dinv    = (float*)carve((size_t)N*4);
  float* xd      = (float*)carve((size_t)N*4);
  float* g       = (float*)carve((size_t)N*4);
  int*   flag    = (int*)  carve(256);
  int*   bsum    = (int*)  carve(1024);
  int*   boff    = (int*)  carve(1024);
  short* Bt      = (short*)carve((size_t)2*8192*8*2);   // 256 KB
  int*   col     = (int*)  carve((size_t)E*4);
  ushort* ts_bf  = (ushort*)carve((size_t)N*HID*2);     // 25.6 MB
  ushort* Abf    = (ushort*)carve((size_t)N*HID*2);     // 25.6 MB
  if (off > ws_size){
    k_diag<<<(out_size+255)/256, 256, 0, stream>>>(out, out_size, (float)(ws_size >> 20));
    return;
  }

  hipMemsetAsync(cnt, 0, (size_t)N*4, stream);
  k_detect<<<1, 256, 0, stream>>>(ei, flag);
  int eblocks = (int)((E + 255) / 256);
  k_count<<<eblocks, 256, 0, stream>>>(ei, E, flag, cnt);
  int nb = (N + 255) / 256;
  k_scan_a<<<nb, 256, 0, stream>>>(cnt, bsum, N);
  k_scan_b<<<1, 256, 0, stream>>>(bsum, boff, nb, row_ptr, N);
  k_scan_c<<<nb, 256, 0, stream>>>(cnt, boff, row_ptr, N);
  k_dinv<<<(N+255)/256, 256, 0, stream>>>(cnt, x, dinv, xd, N);
  hipMemcpyAsync(fill, row_ptr, (size_t)N*4, hipMemcpyDeviceToDevice, stream);
  k_place<<<eblocks, 256, 0, stream>>>(ei, E, flag, fill, col);
  k_splitW<<<32, 256, 0, stream>>>(Wm, Bt);
  k_layer1<<<(N+255)/256, 256, 0, stream>>>(xd, row_ptr, col, g, N);

  int gblocks = (N + 63) / 64;
  int sblocks = (N + 3) / 4;
  // conv2 GEMM (A computed inline from rank-1 conv1 output), then propagate+transform
  k_gemm_mfma<0><<<gblocks, 256, 0, stream>>>(g, Bt, b1, W1, dinv, ts_bf, N);
  k_scatter_bf<0><<<sblocks, 256, 0, stream>>>(ts_bf, row_ptr, col, bm, dinv, Abf, Wc, bc, out, N);
  // conv3..conv9
  for (int l = 0; l < 7; ++l){
    k_gemm_mfma<1><<<gblocks, 256, 0, stream>>>(Abf, Bt, bm, nullptr, dinv, ts_bf, N);
    k_scatter_bf<0><<<sblocks, 256, 0, stream>>>(ts_bf, row_ptr, col, bm, dinv, Abf, Wc, bc, out, N);
  }
  // conv10 + fused readout
  k_gemm_mfma<1><<<gblocks, 256, 0, stream>>>(Abf, Bt, bm, nullptr, dinv, ts_bf, N);
  k_scatter_bf<1><<<sblocks, 256, 0, stream>>>(ts_bf, row_ptr, col, bm, dinv, Abf, Wc, bc, out, N);
}